// Round 7
// baseline (232.398 us; speedup 1.0000x reference)
//
#include <hip/hip_runtime.h>
#include <hip/hip_bf16.h>

// B=4, T=2048, C=1024 single-head causal attention, fp32 in/out.
// R14: double-buffered K-loop (BK=32) with prefetch-before-compute on all
// three GEMM cores. Safe form: one __syncthreads() per K-step does the
// vmcnt/lgkm drain + barrier (no counted vmcnt, no raw barriers — R9's
// race surface eliminated by the invariant "nothing in flight crosses a
// barrier"). LDS unchanged (the old [2] sub-buffers become the dbuf).
// T2 swizzle & fat-wave geometry carried over verbatim from R13.

typedef short bf16x8 __attribute__((ext_vector_type(8)));
typedef float f32x4  __attribute__((ext_vector_type(4)));

#define T_SEQ 2048
#define EMB   1024
#define NBAT  4

struct alignas(8) bh4 { __hip_bfloat16 a, b, c, d; };

__device__ __forceinline__ bh4 pack4(float x, float y, float z, float w) {
    bh4 o { __float2bfloat16(x), __float2bfloat16(y),
            __float2bfloat16(z), __float2bfloat16(w) };
    return o;
}

// ---------------------------------------------------------------- merged cast
__global__ void cast_all(const float* __restrict__ x,
                         const float* __restrict__ w0,
                         const float* __restrict__ w1,
                         const float* __restrict__ w2,
                         __hip_bfloat16* __restrict__ xb,
                         __hip_bfloat16* __restrict__ wb,
                         float* __restrict__ Lbuf) {
    const int bid = blockIdx.x;
    if (bid < 8192) {
        int i = bid * 256 + threadIdx.x;
        float4 v = reinterpret_cast<const float4*>(x)[i];
        reinterpret_cast<bh4*>(xb)[i] = pack4(v.x, v.y, v.z, v.w);
    } else if (bid < 11264) {
        int j = bid - 8192;                       // 0..3071
        int sel = j >> 10;
        const float* src = (sel == 0) ? w0 : (sel == 1) ? w1 : w2;
        int i = (j & 1023) * 256 + threadIdx.x;
        float4 v = reinterpret_cast<const float4*>(src)[i];
        reinterpret_cast<bh4*>(wb + (size_t)sel * 1048576)[i] =
            pack4(v.x, v.y, v.z, v.w);
    } else {
        Lbuf[(bid - 11264) * 256 + threadIdx.x] = 0.f;
    }
}

// ---------------------------------------------------------------- helpers
__device__ __forceinline__ void load_lds16(const void* g, void* l) {
    __builtin_amdgcn_global_load_lds(
        (const __attribute__((address_space(1))) void*)g,
        (__attribute__((address_space(3))) void*)l, 16, 0, 0);
}

// ================================================================ QKV core
// C = A[8192,1024] * B[3072,1024]^T. Block 256x128, 4 waves, wave 128x64.
// Q/K cols -> qkv rows; V cols (ct>=16) -> vT[b][d][t] transposed.
// K-loop: BK=32 double-buffered, stage(t+1) issued before compute(t).
__global__ __launch_bounds__(256, 2) void qkv_gemm(
    const __hip_bfloat16* __restrict__ Abase,
    const __hip_bfloat16* __restrict__ Bbase,
    __hip_bfloat16* __restrict__ qkvOut,
    __hip_bfloat16* __restrict__ vTout)
{
    const int bid = blockIdx.x;               // 0..767 (768 = 8 XCD x 96)
    const int xcd = bid & 7;
    const int ii  = bid >> 3;                 // 0..95
    const int rt  = (xcd << 2) | (ii & 3);    // 0..31 (rows of 256)
    const int ct  = ii >> 2;                  // 0..23 (cols of 128)

    __shared__ short lsA[2][256 * 32];        // dbuf: 2 x 16 KiB
    __shared__ short lsB[2][128 * 32];        // dbuf: 2 x 8 KiB

    const int tid  = threadIdx.x;
    const int wave = tid >> 6;
    const int lane = tid & 63;
    const int wr   = (wave >> 1) * 128;       // wave row base in tile
    const int wc   = (wave &  1) * 64;        // wave col base in tile
    const int sr   = lane >> 2;               // staging row 0..15
    // T2 swizzle (all row-base offsets are 0 mod 16 so they drop out):
    const int scol = ((lane & 3) ^ ((lane >> 3) & 3)) * 8;
    const int frow = lane & 15;
    const int fk   = ((lane >> 4) ^ ((lane >> 1) & 3)) * 8;

    const short* A = (const short*)Abase + (long)rt * 256 * 1024;
    const short* B = (const short*)Bbase + (long)ct * 128 * 1024;
    const short* ga = A + (long)(wave * 64 + sr) * 1024 + scol;
    const short* gb = B + (long)(wave * 32 + sr) * 1024 + scol;

    f32x4 acc[8][4] = {};

    // prologue: stage tile 0 into buf 0, full drain
    load_lds16(ga,         &lsA[0][(wave * 64     ) * 32]);
    load_lds16(ga + 16384, &lsA[0][(wave * 64 + 16) * 32]);
    load_lds16(ga + 32768, &lsA[0][(wave * 64 + 32) * 32]);
    load_lds16(ga + 49152, &lsA[0][(wave * 64 + 48) * 32]);
    load_lds16(gb,         &lsB[0][(wave * 32     ) * 32]);
    load_lds16(gb + 16384, &lsB[0][(wave * 32 + 16) * 32]);
    __syncthreads();

    int cur = 0;
    for (int t = 0; t < 32; ++t) {
        if (t < 31) {                         // prefetch tile t+1 into buf^1
            const int ko = (t + 1) * 32;
            load_lds16(ga + ko,         &lsA[cur ^ 1][(wave * 64     ) * 32]);
            load_lds16(ga + ko + 16384, &lsA[cur ^ 1][(wave * 64 + 16) * 32]);
            load_lds16(ga + ko + 32768, &lsA[cur ^ 1][(wave * 64 + 32) * 32]);
            load_lds16(ga + ko + 49152, &lsA[cur ^ 1][(wave * 64 + 48) * 32]);
            load_lds16(gb + ko,         &lsB[cur ^ 1][(wave * 32     ) * 32]);
            load_lds16(gb + ko + 16384, &lsB[cur ^ 1][(wave * 32 + 16) * 32]);
        }
        bf16x8 af[8], bfr[4];
        #pragma unroll
        for (int m = 0; m < 8; ++m)
            af[m] = *(const bf16x8*)&lsA[cur][(wr + m * 16 + frow) * 32 + fk];
        #pragma unroll
        for (int n = 0; n < 4; ++n)
            bfr[n] = *(const bf16x8*)&lsB[cur][(wc + n * 16 + frow) * 32 + fk];
        #pragma unroll
        for (int m = 0; m < 8; ++m)
            #pragma unroll
            for (int n = 0; n < 4; ++n)
                acc[m][n] = __builtin_amdgcn_mfma_f32_16x16x32_bf16(
                    af[m], bfr[n], acc[m][n], 0, 0, 0);
        __syncthreads();                      // drains vmcnt+lgkm + barrier
        cur ^= 1;
    }

    // epilogue: C/D layout col = lane&15, row = (lane>>4)*4 + reg
    const long crow0 = (long)rt * 256 + wr;
    const long ccol0 = (long)ct * 128 + wc;
    const int  orow  = (lane >> 4) * 4;
    const int  ocol  = lane & 15;

    if (ct >= 16) {
        // V columns: store transposed into vT[b][d][t] (d = col-2048).
        #pragma unroll
        for (int m = 0; m < 8; ++m) {
            const long rowb = crow0 + m * 16 + orow;   // multiple of 4
            const long b    = rowb >> 11;
            const long t0   = rowb & 2047;
            #pragma unroll
            for (int n = 0; n < 4; ++n) {
                const long d = ccol0 + n * 16 + ocol - 2048;
                bh4 pk = pack4(acc[m][n][0], acc[m][n][1],
                               acc[m][n][2], acc[m][n][3]);
                *(bh4*)&vTout[((b << 10) + d) * 2048 + t0] = pk;
            }
        }
    } else {                                  // Q/K columns: plain row store
        #pragma unroll
        for (int m = 0; m < 8; ++m)
            #pragma unroll
            for (int n = 0; n < 4; ++n)
                #pragma unroll
                for (int r = 0; r < 4; ++r)
                    qkvOut[(crow0 + m * 16 + orow + r) * 3072 +
                           ccol0 + n * 16 + ocol] =
                        __float2bfloat16(acc[m][n][r]);
    }
}

// ================================================================ S core
// P = exp(mask(Q K^T)/32) bf16 + atomic rowsums. Fat-wave 256x128 tiles.
// 288 blocks = 8 XCD x 36. xcd -> bz = xcd>>1, half = xcd&1.
// j = half*36 + (bid>>3) in 0..71; rt s.t. j in [rt(rt+1),(rt+1)(rt+2)),
// ct = j - rt(rt+1). K-loop: BK=32 dbuf, prefetch-before-compute.
__global__ __launch_bounds__(256, 2) void s_gemm(
    const __hip_bfloat16* __restrict__ QKV,
    __hip_bfloat16* __restrict__ P,
    float* __restrict__ Lbuf)
{
    const int bid  = blockIdx.x;              // 0..287
    const int xcd  = bid & 7;
    const int bz   = xcd >> 1;
    int j = (xcd & 1) * 36 + (bid >> 3);      // 0..71
    int rt = 0;
    while (j >= (rt + 1) * (rt + 2)) ++rt;    // <= 7 iterations
    const int ct = j - rt * (rt + 1);

    __shared__ short lsA[2][256 * 32];        // dbuf
    __shared__ short lsB[2][128 * 32];

    const int tid  = threadIdx.x;
    const int wave = tid >> 6;
    const int lane = tid & 63;
    const int wr   = (wave >> 1) * 128;
    const int wc   = (wave &  1) * 64;
    const int sr   = lane >> 2;
    const int scol = ((lane & 3) ^ ((lane >> 3) & 3)) * 8;   // T2 swizzle
    const int frow = lane & 15;
    const int fk   = ((lane >> 4) ^ ((lane >> 1) & 3)) * 8;

    const short* A = (const short*)QKV + (long)bz * 6291456
                   + (long)rt * 256 * 3072;            // Q rows
    const short* B = (const short*)QKV + (long)bz * 6291456 + 1024
                   + (long)ct * 128 * 3072;            // K rows
    const short* ga = A + (long)(wave * 64 + sr) * 3072 + scol;
    const short* gb = B + (long)(wave * 32 + sr) * 3072 + scol;

    f32x4 acc[8][4] = {};

    load_lds16(ga,          &lsA[0][(wave * 64     ) * 32]);
    load_lds16(ga +  49152, &lsA[0][(wave * 64 + 16) * 32]);
    load_lds16(ga +  98304, &lsA[0][(wave * 64 + 32) * 32]);
    load_lds16(ga + 147456, &lsA[0][(wave * 64 + 48) * 32]);
    load_lds16(gb,          &lsB[0][(wave * 32     ) * 32]);
    load_lds16(gb +  49152, &lsB[0][(wave * 32 + 16) * 32]);
    __syncthreads();

    int cur = 0;
    for (int t = 0; t < 32; ++t) {
        if (t < 31) {
            const int ko = (t + 1) * 32;
            load_lds16(ga + ko,          &lsA[cur ^ 1][(wave * 64     ) * 32]);
            load_lds16(ga + ko +  49152, &lsA[cur ^ 1][(wave * 64 + 16) * 32]);
            load_lds16(ga + ko +  98304, &lsA[cur ^ 1][(wave * 64 + 32) * 32]);
            load_lds16(ga + ko + 147456, &lsA[cur ^ 1][(wave * 64 + 48) * 32]);
            load_lds16(gb + ko,          &lsB[cur ^ 1][(wave * 32     ) * 32]);
            load_lds16(gb + ko +  49152, &lsB[cur ^ 1][(wave * 32 + 16) * 32]);
        }
        bf16x8 af[8], bfr[4];
        #pragma unroll
        for (int m = 0; m < 8; ++m)
            af[m] = *(const bf16x8*)&lsA[cur][(wr + m * 16 + frow) * 32 + fk];
        #pragma unroll
        for (int n = 0; n < 4; ++n)
            bfr[n] = *(const bf16x8*)&lsB[cur][(wc + n * 16 + frow) * 32 + fk];
        #pragma unroll
        for (int m = 0; m < 8; ++m)
            #pragma unroll
            for (int n = 0; n < 4; ++n)
                acc[m][n] = __builtin_amdgcn_mfma_f32_16x16x32_bf16(
                    af[m], bfr[n], acc[m][n], 0, 0, 0);
        __syncthreads();
        cur ^= 1;
    }

    // epilogue: exp(s/32) masked + per-row sums (scalar rowsum per (m,r))
    const long crow0 = (long)rt * 256 + wr;
    const long ccol0 = (long)ct * 128 + wc;
    const int  orow  = (lane >> 4) * 4;
    const int  ocol  = lane & 15;
    __hip_bfloat16* C = P + (long)bz * 4194304;

    #pragma unroll
    for (int m = 0; m < 8; ++m)
        #pragma unroll
        for (int r = 0; r < 4; ++r) {
            const long row = crow0 + m * 16 + orow + r;
            float sum = 0.f;
            #pragma unroll
            for (int n = 0; n < 4; ++n) {
                const long col = ccol0 + n * 16 + ocol;
                float p = (col <= row) ? __expf(acc[m][n][r] * 0.03125f) : 0.f;
                C[row * 2048 + col] = __float2bfloat16(p);
                sum += p;
            }
            sum += __shfl_xor(sum, 1);
            sum += __shfl_xor(sum, 2);
            sum += __shfl_xor(sum, 4);
            sum += __shfl_xor(sum, 8);
            if ((lane & 15) == 0)
                atomicAdd(&Lbuf[bz * T_SEQ + row], sum);
        }
}

// ---------------------------------------------------------------- PV split-K
// 768 blocks = 8 XCD-groups x 96. xcd -> (bz = xcd>>1, half = xcd&1).
// idx = bid>>3: p = idx>>3 (0..11), ct = idx&7.
// half0: p<8  -> direct rt=p, full K, scaled -> d_out  (vT t<1024 only)
//        p>=8 -> part0 rt=p (8..11), K tiles [0,8)     -> d_out unscaled
// half1: p<4  -> part0 rt=12+p, K tiles [0,8)          -> d_out unscaled
//        p>=4 -> part1 rt=8+(p-4)=4+p, K [1024,(rt+1)*128) -> tmp1
// K-loop: BK=32 dbuf, prefetch-before-compute.
__global__ __launch_bounds__(256) void pv_split(
    const __hip_bfloat16* __restrict__ P,
    const __hip_bfloat16* __restrict__ Vt,
    float* __restrict__ out,
    float* __restrict__ tmp1,
    const float* __restrict__ Lbuf)
{
    const int bid  = blockIdx.x;             // 0..767
    const int xcd  = bid & 7;
    const int bz   = xcd >> 1;
    const int half = xcd & 1;
    const int idx  = bid >> 3;               // 0..95
    const int p    = idx >> 3;               // 0..11
    const int ct   = idx & 7;

    int rt, k0s, k0e;
    bool scaled = false;
    float* dst;
    if (half == 0) {
        if (p < 8) {
            rt = p; k0s = 0; k0e = (rt + 1) * 128; scaled = true;
            dst = out + (long)bz * 2097152 + (long)rt * 128 * 1024;
        } else {
            rt = p;  // 8..11
            k0s = 0; k0e = 1024;
            dst = out + (long)bz * 2097152 + (long)rt * 128 * 1024;
        }
    } else {
        if (p < 4) {
            rt = 12 + p; k0s = 0; k0e = 1024;
            dst = out + (long)bz * 2097152 + (long)rt * 128 * 1024;
        } else {
            rt = 4 + p;  // 8..15
            k0s = 1024; k0e = (rt + 1) * 128;
            dst = tmp1 + ((long)bz * 1024 + (long)(rt - 8) * 128) * 1024;
        }
    }

    __shared__ short lsA[2][128 * 32];       // dbuf
    __shared__ short lsB[2][128 * 32];

    const int tid  = threadIdx.x;
    const int wave = tid >> 6;
    const int lane = tid & 63;
    const int wr   = (wave >> 1) * 64;
    const int wc   = (wave &  1) * 64;
    const int srow = wave * 32 + (lane >> 2);
    const int scol = ((lane & 3) ^ ((lane >> 3) & 3)) * 8;   // T2 swizzle
    const int frow = lane & 15;
    const int fk   = ((lane >> 4) ^ ((lane >> 1) & 3)) * 8;

    const short* A = (const short*)P  + (long)bz * 4194304 + (long)rt * 128 * 2048;
    const short* B = (const short*)Vt + (long)bz * 2097152 + (long)ct * 128 * 2048;
    const short* ga = A + (long)srow * 2048 + scol;
    const short* gb = B + (long)srow * 2048 + scol;

    f32x4 acc[4][4] = {};

    const int nt = (k0e - k0s) >> 5;         // 32-K steps

    load_lds16(ga + k0s,         &lsA[0][(wave * 32     ) * 32]);
    load_lds16(ga + k0s + 32768, &lsA[0][(wave * 32 + 16) * 32]);
    load_lds16(gb + k0s,         &lsB[0][(wave * 32     ) * 32]);
    load_lds16(gb + k0s + 32768, &lsB[0][(wave * 32 + 16) * 32]);
    __syncthreads();

    int cur = 0;
    for (int t = 0; t < nt; ++t) {
        if (t + 1 < nt) {
            const int ko = k0s + (t + 1) * 32;
            load_lds16(ga + ko,         &lsA[cur ^ 1][(wave * 32     ) * 32]);
            load_lds16(ga + ko + 32768, &lsA[cur ^ 1][(wave * 32 + 16) * 32]);
            load_lds16(gb + ko,         &lsB[cur ^ 1][(wave * 32     ) * 32]);
            load_lds16(gb + ko + 32768, &lsB[cur ^ 1][(wave * 32 + 16) * 32]);
        }
        bf16x8 af[4], bfr[4];
        #pragma unroll
        for (int m = 0; m < 4; ++m)
            af[m] = *(const bf16x8*)&lsA[cur][(wr + m * 16 + frow) * 32 + fk];
        #pragma unroll
        for (int n = 0; n < 4; ++n)
            bfr[n] = *(const bf16x8*)&lsB[cur][(wc + n * 16 + frow) * 32 + fk];
        #pragma unroll
        for (int m = 0; m < 4; ++m)
            #pragma unroll
            for (int n = 0; n < 4; ++n)
                acc[m][n] = __builtin_amdgcn_mfma_f32_16x16x32_bf16(
                    af[m], bfr[n], acc[m][n], 0, 0, 0);
        __syncthreads();
        cur ^= 1;
    }

    const int orow = (lane >> 4) * 4;
    const int ocol = lane & 15;
    if (scaled) {
        const float* il = Lbuf + bz * T_SEQ + (long)rt * 128;
        #pragma unroll
        for (int m = 0; m < 4; ++m)
            #pragma unroll
            for (int r = 0; r < 4; ++r) {
                const long lrow = wr + m * 16 + orow + r;
                const float s = 1.f / il[lrow];
                #pragma unroll
                for (int n = 0; n < 4; ++n)
                    dst[lrow * 1024 + ct * 128 + wc + n * 16 + ocol] =
                        acc[m][n][r] * s;
            }
    } else {
        #pragma unroll
        for (int m = 0; m < 4; ++m)
            #pragma unroll
            for (int r = 0; r < 4; ++r) {
                const long lrow = wr + m * 16 + orow + r;
                #pragma unroll
                for (int n = 0; n < 4; ++n)
                    dst[lrow * 1024 + ct * 128 + wc + n * 16 + ocol] = acc[m][n][r];
            }
    }
}

// ---------------------------------------------------------------- PV finish
// rows >= 1024 per batch: out = (out + tmp1) / l.
__global__ void pv_finish(float* __restrict__ out,
                          const float* __restrict__ tmp1,
                          const float* __restrict__ Lbuf) {
    const int g = blockIdx.x;                // 0..4095
    const int b = g >> 10;
    const int r = (g & 1023) + 1024;
    const int c = threadIdx.x * 4;
    const float s = 1.f / Lbuf[b * T_SEQ + r];
    float* po = out + (long)b * 2097152 + (long)r * 1024 + c;
    float4 o = *(const float4*)po;
    float4 t = *(const float4*)&tmp1[((long)b * 1024 + (r - 1024)) * 1024 + c];
    o.x = (o.x + t.x) * s; o.y = (o.y + t.y) * s;
    o.z = (o.z + t.z) * s; o.w = (o.w + t.w) * s;
    *(float4*)po = o;
}

// ---------------------------------------------------------------- launch
extern "C" void kernel_launch(void* const* d_in, const int* in_sizes, int n_in,
                              void* d_out, int out_size, void* d_ws, size_t ws_size,
                              hipStream_t stream) {
    const float* x  = (const float*)d_in[0];
    const float* Wq = (const float*)d_in[1];
    const float* Wk = (const float*)d_in[2];
    const float* Wv = (const float*)d_in[3];

    char* ws = (char*)d_ws;
    // workspace (bytes):
    //   xb   @ 0         : 16,777,216   (dead after QKV; tmp1 aliases)
    //   wb   @ 16777216  :  6,291,456
    //   qkv  @ 23068672  : 50,331,648   (Q|K cols used; V cols unwritten)
    //   vT   @ 73400320  : 16,777,216
    //   P    @ 90177536  : 33,554,432
    //   l    @ 123731968 :     32,768
    __hip_bfloat16* xb   = (__hip_bfloat16*)(ws);
    __hip_bfloat16* wb   = (__hip_bfloat16*)(ws + 16777216);
    __hip_bfloat16* qkv  = (__hip_bfloat16*)(ws + 23068672);
    __hip_bfloat16* vT   = (__hip_bfloat16*)(ws + 73400320);
    __hip_bfloat16* P    = (__hip_bfloat16*)(ws + 90177536);
    float*          Lbuf = (float*)        (ws + 123731968);
    float*          tmp1 = (float*)        (ws);              // aliases xb

    // 1) casts + Lbuf zero
    cast_all<<<dim3(11296), 256, 0, stream>>>(x, Wq, Wk, Wv, xb, wb, Lbuf);

    // 2) fused QKV; fat-wave 256x128 core. Q/K -> qkv, V -> vT transposed
    qkv_gemm<<<dim3(768), 256, 0, stream>>>(xb, wb, qkv, vT);

    // 3) P = exp(mask(QK^T)/32) bf16 + atomic rowsums; fat-wave triangle
    s_gemm<<<dim3(288), 256, 0, stream>>>(qkv, P, Lbuf);

    // 4) O = P @ V ; XCD-grouped split-K, direct rows scaled in-epilogue
    pv_split<<<dim3(768), 256, 0, stream>>>(
        P, vT, (float*)d_out, tmp1, Lbuf);

    // 5) combine + scale split rows
    pv_finish<<<dim3(4096), 256, 0, stream>>>((float*)d_out, tmp1, Lbuf);
}

// Round 8
// 211.192 us; speedup vs baseline: 1.1004x; 1.1004x over previous
//
#include <hip/hip_runtime.h>
#include <hip/hip_bf16.h>

// B=4, T=2048, C=1024 single-head causal attention, fp32 in/out.
// R15: revert to the R13 cores (R14's explicit dbuf regressed: __syncthreads
// drains vmcnt(0), so prefetch dies at the same-iteration barrier — m99/m100
// reproduced). Micro-adjustments only: B-panel (long-latency L3) loads issued
// before A loads in qkv/s staging; pv_split gets __launch_bounds__(256,3).

typedef short bf16x8 __attribute__((ext_vector_type(8)));
typedef float f32x4  __attribute__((ext_vector_type(4)));

#define T_SEQ 2048
#define EMB   1024
#define NBAT  4

struct alignas(8) bh4 { __hip_bfloat16 a, b, c, d; };

__device__ __forceinline__ bh4 pack4(float x, float y, float z, float w) {
    bh4 o { __float2bfloat16(x), __float2bfloat16(y),
            __float2bfloat16(z), __float2bfloat16(w) };
    return o;
}

// ---------------------------------------------------------------- merged cast
__global__ void cast_all(const float* __restrict__ x,
                         const float* __restrict__ w0,
                         const float* __restrict__ w1,
                         const float* __restrict__ w2,
                         __hip_bfloat16* __restrict__ xb,
                         __hip_bfloat16* __restrict__ wb,
                         float* __restrict__ Lbuf) {
    const int bid = blockIdx.x;
    if (bid < 8192) {
        int i = bid * 256 + threadIdx.x;
        float4 v = reinterpret_cast<const float4*>(x)[i];
        reinterpret_cast<bh4*>(xb)[i] = pack4(v.x, v.y, v.z, v.w);
    } else if (bid < 11264) {
        int j = bid - 8192;                       // 0..3071
        int sel = j >> 10;
        const float* src = (sel == 0) ? w0 : (sel == 1) ? w1 : w2;
        int i = (j & 1023) * 256 + threadIdx.x;
        float4 v = reinterpret_cast<const float4*>(src)[i];
        reinterpret_cast<bh4*>(wb + (size_t)sel * 1048576)[i] =
            pack4(v.x, v.y, v.z, v.w);
    } else {
        Lbuf[(bid - 11264) * 256 + threadIdx.x] = 0.f;
    }
}

// ---------------------------------------------------------------- helpers
__device__ __forceinline__ void load_lds16(const void* g, void* l) {
    __builtin_amdgcn_global_load_lds(
        (const __attribute__((address_space(1))) void*)g,
        (__attribute__((address_space(3))) void*)l, 16, 0, 0);
}

// ================================================================ QKV core
// C = A[8192,1024] * B[3072,1024]^T. Block 256x128, 4 waves, wave 128x64.
// Q/K cols -> qkv rows; V cols (ct>=16) -> vT[b][d][t] transposed.
__global__ __launch_bounds__(256, 2) void qkv_gemm(
    const __hip_bfloat16* __restrict__ Abase,
    const __hip_bfloat16* __restrict__ Bbase,
    __hip_bfloat16* __restrict__ qkvOut,
    __hip_bfloat16* __restrict__ vTout)
{
    const int bid = blockIdx.x;               // 0..767 (768 = 8 XCD x 96)
    const int xcd = bid & 7;
    const int ii  = bid >> 3;                 // 0..95
    const int rt  = (xcd << 2) | (ii & 3);    // 0..31 (rows of 256)
    const int ct  = ii >> 2;                  // 0..23 (cols of 128)

    __shared__ short lsA[2][256 * 32];        // 32 KiB
    __shared__ short lsB[2][128 * 32];        // 16 KiB

    const int tid  = threadIdx.x;
    const int wave = tid >> 6;
    const int lane = tid & 63;
    const int wr   = (wave >> 1) * 128;       // wave row base in tile
    const int wc   = (wave &  1) * 64;        // wave col base in tile
    const int sr   = lane >> 2;               // staging row 0..15
    // T2 swizzle (all row-base offsets are 0 mod 16 so they drop out):
    const int scol = ((lane & 3) ^ ((lane >> 3) & 3)) * 8;
    const int frow = lane & 15;
    const int fk   = ((lane >> 4) ^ ((lane >> 1) & 3)) * 8;

    const short* A = (const short*)Abase + (long)rt * 256 * 1024;
    const short* B = (const short*)Bbase + (long)ct * 128 * 1024;

    f32x4 acc[8][4] = {};

    for (int k0 = 0; k0 < 1024; k0 += 64) {
        const short* ga = A + (long)(wave * 64 + sr) * 1024 + k0 + scol;
        const short* gb = B + (long)(wave * 32 + sr) * 1024 + k0 + scol;
        // B (W-panel, L3-latency) first so its latency leads the drain.
        #pragma unroll
        for (int i = 0; i < 2; ++i) {
            load_lds16(gb + (long)i * 16384,      &lsB[0][(wave * 32 + i * 16) * 32]);
            load_lds16(gb + (long)i * 16384 + 32, &lsB[1][(wave * 32 + i * 16) * 32]);
        }
        #pragma unroll
        for (int i = 0; i < 4; ++i) {
            load_lds16(ga + (long)i * 16384,      &lsA[0][(wave * 64 + i * 16) * 32]);
            load_lds16(ga + (long)i * 16384 + 32, &lsA[1][(wave * 64 + i * 16) * 32]);
        }
        __syncthreads();

        #pragma unroll
        for (int sub = 0; sub < 2; ++sub) {
            bf16x8 af[8], bfr[4];
            #pragma unroll
            for (int m = 0; m < 8; ++m)
                af[m] = *(const bf16x8*)&lsA[sub][(wr + m * 16 + frow) * 32 + fk];
            #pragma unroll
            for (int n = 0; n < 4; ++n)
                bfr[n] = *(const bf16x8*)&lsB[sub][(wc + n * 16 + frow) * 32 + fk];
            #pragma unroll
            for (int m = 0; m < 8; ++m)
                #pragma unroll
                for (int n = 0; n < 4; ++n)
                    acc[m][n] = __builtin_amdgcn_mfma_f32_16x16x32_bf16(
                        af[m], bfr[n], acc[m][n], 0, 0, 0);
        }
        __syncthreads();
    }

    // epilogue: C/D layout col = lane&15, row = (lane>>4)*4 + reg
    const long crow0 = (long)rt * 256 + wr;
    const long ccol0 = (long)ct * 128 + wc;
    const int  orow  = (lane >> 4) * 4;
    const int  ocol  = lane & 15;

    if (ct >= 16) {
        // V columns: store transposed into vT[b][d][t] (d = col-2048).
        #pragma unroll
        for (int m = 0; m < 8; ++m) {
            const long rowb = crow0 + m * 16 + orow;   // multiple of 4
            const long b    = rowb >> 11;
            const long t0   = rowb & 2047;
            #pragma unroll
            for (int n = 0; n < 4; ++n) {
                const long d = ccol0 + n * 16 + ocol - 2048;
                bh4 pk = pack4(acc[m][n][0], acc[m][n][1],
                               acc[m][n][2], acc[m][n][3]);
                *(bh4*)&vTout[((b << 10) + d) * 2048 + t0] = pk;
            }
        }
    } else {                                  // Q/K columns: plain row store
        #pragma unroll
        for (int m = 0; m < 8; ++m)
            #pragma unroll
            for (int n = 0; n < 4; ++n)
                #pragma unroll
                for (int r = 0; r < 4; ++r)
                    qkvOut[(crow0 + m * 16 + orow + r) * 3072 +
                           ccol0 + n * 16 + ocol] =
                        __float2bfloat16(acc[m][n][r]);
    }
}

// ================================================================ S core
// P = exp(mask(Q K^T)/32) bf16 + atomic rowsums. Fat-wave 256x128 tiles.
// 288 blocks = 8 XCD x 36. xcd -> bz = xcd>>1, half = xcd&1.
// j = half*36 + (bid>>3) in 0..71; tile j of batch bz's triangle:
// rt s.t. j in [rt(rt+1), (rt+1)(rt+2)), ct = j - rt(rt+1)  (ct <= 2rt+1).
__global__ __launch_bounds__(256, 2) void s_gemm(
    const __hip_bfloat16* __restrict__ QKV,
    __hip_bfloat16* __restrict__ P,
    float* __restrict__ Lbuf)
{
    const int bid  = blockIdx.x;              // 0..287
    const int xcd  = bid & 7;
    const int bz   = xcd >> 1;
    int j = (xcd & 1) * 36 + (bid >> 3);      // 0..71
    int rt = 0;
    while (j >= (rt + 1) * (rt + 2)) ++rt;    // <= 7 iterations
    const int ct = j - rt * (rt + 1);

    __shared__ short lsA[2][256 * 32];        // 32 KiB
    __shared__ short lsB[2][128 * 32];        // 16 KiB

    const int tid  = threadIdx.x;
    const int wave = tid >> 6;
    const int lane = tid & 63;
    const int wr   = (wave >> 1) * 128;
    const int wc   = (wave &  1) * 64;
    const int sr   = lane >> 2;
    const int scol = ((lane & 3) ^ ((lane >> 3) & 3)) * 8;   // T2 swizzle
    const int frow = lane & 15;
    const int fk   = ((lane >> 4) ^ ((lane >> 1) & 3)) * 8;

    const short* A = (const short*)QKV + (long)bz * 6291456
                   + (long)rt * 256 * 3072;            // Q rows
    const short* B = (const short*)QKV + (long)bz * 6291456 + 1024
                   + (long)ct * 128 * 3072;            // K rows

    f32x4 acc[8][4] = {};

    for (int k0 = 0; k0 < 1024; k0 += 64) {
        const short* ga = A + (long)(wave * 64 + sr) * 3072 + k0 + scol;
        const short* gb = B + (long)(wave * 32 + sr) * 3072 + k0 + scol;
        #pragma unroll
        for (int i = 0; i < 2; ++i) {
            load_lds16(gb + (long)i * 49152,      &lsB[0][(wave * 32 + i * 16) * 32]);
            load_lds16(gb + (long)i * 49152 + 32, &lsB[1][(wave * 32 + i * 16) * 32]);
        }
        #pragma unroll
        for (int i = 0; i < 4; ++i) {
            load_lds16(ga + (long)i * 49152,      &lsA[0][(wave * 64 + i * 16) * 32]);
            load_lds16(ga + (long)i * 49152 + 32, &lsA[1][(wave * 64 + i * 16) * 32]);
        }
        __syncthreads();

        #pragma unroll
        for (int sub = 0; sub < 2; ++sub) {
            bf16x8 af[8], bfr[4];
            #pragma unroll
            for (int m = 0; m < 8; ++m)
                af[m] = *(const bf16x8*)&lsA[sub][(wr + m * 16 + frow) * 32 + fk];
            #pragma unroll
            for (int n = 0; n < 4; ++n)
                bfr[n] = *(const bf16x8*)&lsB[sub][(wc + n * 16 + frow) * 32 + fk];
            #pragma unroll
            for (int m = 0; m < 8; ++m)
                #pragma unroll
                for (int n = 0; n < 4; ++n)
                    acc[m][n] = __builtin_amdgcn_mfma_f32_16x16x32_bf16(
                        af[m], bfr[n], acc[m][n], 0, 0, 0);
        }
        __syncthreads();
    }

    // epilogue: exp(s/32) masked + per-row sums (scalar rowsum per (m,r))
    const long crow0 = (long)rt * 256 + wr;
    const long ccol0 = (long)ct * 128 + wc;
    const int  orow  = (lane >> 4) * 4;
    const int  ocol  = lane & 15;
    __hip_bfloat16* C = P + (long)bz * 4194304;

    #pragma unroll
    for (int m = 0; m < 8; ++m)
        #pragma unroll
        for (int r = 0; r < 4; ++r) {
            const long row = crow0 + m * 16 + orow + r;
            float sum = 0.f;
            #pragma unroll
            for (int n = 0; n < 4; ++n) {
                const long col = ccol0 + n * 16 + ocol;
                float p = (col <= row) ? __expf(acc[m][n][r] * 0.03125f) : 0.f;
                C[row * 2048 + col] = __float2bfloat16(p);
                sum += p;
            }
            sum += __shfl_xor(sum, 1);
            sum += __shfl_xor(sum, 2);
            sum += __shfl_xor(sum, 4);
            sum += __shfl_xor(sum, 8);
            if ((lane & 15) == 0)
                atomicAdd(&Lbuf[bz * T_SEQ + row], sum);
        }
}

// ---------------------------------------------------------------- PV split-K
// 768 blocks = 8 XCD-groups x 96. xcd -> (bz = xcd>>1, half = xcd&1).
// idx = bid>>3: p = idx>>3 (0..11), ct = idx&7.
// half0: p<8  -> direct rt=p, full K, scaled -> d_out  (vT t<1024 only)
//        p>=8 -> part0 rt=p (8..11), K tiles [0,8)     -> d_out unscaled
// half1: p<4  -> part0 rt=12+p, K tiles [0,8)          -> d_out unscaled
//        p>=4 -> part1 rt=8+(p-4)=4+p, K [1024,(rt+1)*128) -> tmp1
// Both halves: 68 K-tiles of work. pv_finish combines rows >= 1024.
__global__ __launch_bounds__(256, 3) void pv_split(
    const __hip_bfloat16* __restrict__ P,
    const __hip_bfloat16* __restrict__ Vt,
    float* __restrict__ out,
    float* __restrict__ tmp1,
    const float* __restrict__ Lbuf)
{
    const int bid  = blockIdx.x;             // 0..767
    const int xcd  = bid & 7;
    const int bz   = xcd >> 1;
    const int half = xcd & 1;
    const int idx  = bid >> 3;               // 0..95
    const int p    = idx >> 3;               // 0..11
    const int ct   = idx & 7;

    int rt, k0s, k0e;
    bool scaled = false;
    float* dst;
    if (half == 0) {
        if (p < 8) {
            rt = p; k0s = 0; k0e = (rt + 1) * 128; scaled = true;
            dst = out + (long)bz * 2097152 + (long)rt * 128 * 1024;
        } else {
            rt = p;  // 8..11
            k0s = 0; k0e = 1024;
            dst = out + (long)bz * 2097152 + (long)rt * 128 * 1024;
        }
    } else {
        if (p < 4) {
            rt = 12 + p; k0s = 0; k0e = 1024;
            dst = out + (long)bz * 2097152 + (long)rt * 128 * 1024;
        } else {
            rt = 4 + p;  // 8..15
            k0s = 1024; k0e = (rt + 1) * 128;
            dst = tmp1 + ((long)bz * 1024 + (long)(rt - 8) * 128) * 1024;
        }
    }

    __shared__ short lsA[2][128 * 32];
    __shared__ short lsB[2][128 * 32];

    const int tid  = threadIdx.x;
    const int wave = tid >> 6;
    const int lane = tid & 63;
    const int wr   = (wave >> 1) * 64;
    const int wc   = (wave &  1) * 64;
    const int srow = wave * 32 + (lane >> 2);
    const int scol = ((lane & 3) ^ ((lane >> 3) & 3)) * 8;   // T2 swizzle
    const int frow = lane & 15;
    const int fk   = ((lane >> 4) ^ ((lane >> 1) & 3)) * 8;

    const short* A = (const short*)P  + (long)bz * 4194304 + (long)rt * 128 * 2048;
    const short* B = (const short*)Vt + (long)bz * 2097152 + (long)ct * 128 * 2048;

    f32x4 acc[4][4] = {};

    for (int k0 = k0s; k0 < k0e; k0 += 64) {
        const short* ga = A + (long)srow * 2048 + k0 + scol;
        const short* gb = B + (long)srow * 2048 + k0 + scol;
        load_lds16(gb,                   &lsB[0][(wave * 32) * 32]);
        load_lds16(gb + 16L * 2048,      &lsB[0][(wave * 32 + 16) * 32]);
        load_lds16(gb + 32,              &lsB[1][(wave * 32) * 32]);
        load_lds16(gb + 16L * 2048 + 32, &lsB[1][(wave * 32 + 16) * 32]);
        load_lds16(ga,                   &lsA[0][(wave * 32) * 32]);
        load_lds16(ga + 16L * 2048,      &lsA[0][(wave * 32 + 16) * 32]);
        load_lds16(ga + 32,              &lsA[1][(wave * 32) * 32]);
        load_lds16(ga + 16L * 2048 + 32, &lsA[1][(wave * 32 + 16) * 32]);
        __syncthreads();

        #pragma unroll
        for (int sub = 0; sub < 2; ++sub) {
            bf16x8 af[4], bfr[4];
            #pragma unroll
            for (int m = 0; m < 4; ++m)
                af[m] = *(const bf16x8*)&lsA[sub][(wr + m * 16 + frow) * 32 + fk];
            #pragma unroll
            for (int n = 0; n < 4; ++n)
                bfr[n] = *(const bf16x8*)&lsB[sub][(wc + n * 16 + frow) * 32 + fk];
            #pragma unroll
            for (int m = 0; m < 4; ++m)
                #pragma unroll
                for (int n = 0; n < 4; ++n)
                    acc[m][n] = __builtin_amdgcn_mfma_f32_16x16x32_bf16(
                        af[m], bfr[n], acc[m][n], 0, 0, 0);
        }
        __syncthreads();
    }

    const int orow = (lane >> 4) * 4;
    const int ocol = lane & 15;
    if (scaled) {
        const float* il = Lbuf + bz * T_SEQ + (long)rt * 128;
        #pragma unroll
        for (int m = 0; m < 4; ++m)
            #pragma unroll
            for (int r = 0; r < 4; ++r) {
                const long lrow = wr + m * 16 + orow + r;
                const float s = 1.f / il[lrow];
                #pragma unroll
                for (int n = 0; n < 4; ++n)
                    dst[lrow * 1024 + ct * 128 + wc + n * 16 + ocol] =
                        acc[m][n][r] * s;
            }
    } else {
        #pragma unroll
        for (int m = 0; m < 4; ++m)
            #pragma unroll
            for (int r = 0; r < 4; ++r) {
                const long lrow = wr + m * 16 + orow + r;
                #pragma unroll
                for (int n = 0; n < 4; ++n)
                    dst[lrow * 1024 + ct * 128 + wc + n * 16 + ocol] = acc[m][n][r];
            }
    }
}

// ---------------------------------------------------------------- PV finish
// rows >= 1024 per batch: out = (out + tmp1) / l.
__global__ void pv_finish(float* __restrict__ out,
                          const float* __restrict__ tmp1,
                          const float* __restrict__ Lbuf) {
    const int g = blockIdx.x;                // 0..4095
    const int b = g >> 10;
    const int r = (g & 1023) + 1024;
    const int c = threadIdx.x * 4;
    const float s = 1.f / Lbuf[b * T_SEQ + r];
    float* po = out + (long)b * 2097152 + (long)r * 1024 + c;
    float4 o = *(const float4*)po;
    float4 t = *(const float4*)&tmp1[((long)b * 1024 + (r - 1024)) * 1024 + c];
    o.x = (o.x + t.x) * s; o.y = (o.y + t.y) * s;
    o.z = (o.z + t.z) * s; o.w = (o.w + t.w) * s;
    *(float4*)po = o;
}

// ---------------------------------------------------------------- launch
extern "C" void kernel_launch(void* const* d_in, const int* in_sizes, int n_in,
                              void* d_out, int out_size, void* d_ws, size_t ws_size,
                              hipStream_t stream) {
    const float* x  = (const float*)d_in[0];
    const float* Wq = (const float*)d_in[1];
    const float* Wk = (const float*)d_in[2];
    const float* Wv = (const float*)d_in[3];

    char* ws = (char*)d_ws;
    // workspace (bytes):
    //   xb   @ 0         : 16,777,216   (dead after QKV; tmp1 aliases)
    //   wb   @ 16777216  :  6,291,456
    //   qkv  @ 23068672  : 50,331,648   (Q|K cols used; V cols unwritten)
    //   vT   @ 73400320  : 16,777,216
    //   P    @ 90177536  : 33,554,432
    //   l    @ 123731968 :     32,768
    __hip_bfloat16* xb   = (__hip_bfloat16*)(ws);
    __hip_bfloat16* wb   = (__hip_bfloat16*)(ws + 16777216);
    __hip_bfloat16* qkv  = (__hip_bfloat16*)(ws + 23068672);
    __hip_bfloat16* vT   = (__hip_bfloat16*)(ws + 73400320);
    __hip_bfloat16* P    = (__hip_bfloat16*)(ws + 90177536);
    float*          Lbuf = (float*)        (ws + 123731968);
    float*          tmp1 = (float*)        (ws);              // aliases xb

    // 1) casts + Lbuf zero
    cast_all<<<dim3(11296), 256, 0, stream>>>(x, Wq, Wk, Wv, xb, wb, Lbuf);

    // 2) fused QKV; fat-wave 256x128 core. Q/K -> qkv, V -> vT transposed
    qkv_gemm<<<dim3(768), 256, 0, stream>>>(xb, wb, qkv, vT);

    // 3) P = exp(mask(QK^T)/32) bf16 + atomic rowsums; fat-wave triangle
    s_gemm<<<dim3(288), 256, 0, stream>>>(qkv, P, Lbuf);

    // 4) O = P @ V ; XCD-grouped split-K, direct rows scaled in-epilogue
    pv_split<<<dim3(768), 256, 0, stream>>>(
        P, vT, (float*)d_out, tmp1, Lbuf);

    // 5) combine + scale split rows
    pv_finish<<<dim3(4096), 256, 0, stream>>>((float*)d_out, tmp1, Lbuf);
}

// Round 9
// 207.000 us; speedup vs baseline: 1.1227x; 1.0202x over previous
//
#include <hip/hip_runtime.h>
#include <hip/hip_bf16.h>

// B=4, T=2048, C=1024 single-head causal attention, fp32 in/out.
// R16: s_gemm back to the thin 128x128 core (R11's proven swizzled core,
// 544 blocks, S_RT0/S_RT1 triangle) with __launch_bounds__(256,3):
// thin waves (~148 regs) allow 3 blocks/CU -> all 68 blocks/XCD
// co-resident, 2-3-way TLP, no solo-block stalls / serial tail that the
// 288-block fat-S suffered. Scalar rowsum epilogue keeps regs under the
// 3-deep cap. pv_split: balanced p-remap (each dispatch-triple = 17 units).
// qkv_gemm (fat, B-first) / pv_finish / cast_all frozen from R15.

typedef short bf16x8 __attribute__((ext_vector_type(8)));
typedef float f32x4  __attribute__((ext_vector_type(4)));

#define T_SEQ 2048
#define EMB   1024
#define NBAT  4

struct alignas(8) bh4 { __hip_bfloat16 a, b, c, d; };

__device__ __forceinline__ bh4 pack4(float x, float y, float z, float w) {
    bh4 o { __float2bfloat16(x), __float2bfloat16(y),
            __float2bfloat16(z), __float2bfloat16(w) };
    return o;
}

// ---------------------------------------------------------------- merged cast
__global__ void cast_all(const float* __restrict__ x,
                         const float* __restrict__ w0,
                         const float* __restrict__ w1,
                         const float* __restrict__ w2,
                         __hip_bfloat16* __restrict__ xb,
                         __hip_bfloat16* __restrict__ wb,
                         float* __restrict__ Lbuf) {
    const int bid = blockIdx.x;
    if (bid < 8192) {
        int i = bid * 256 + threadIdx.x;
        float4 v = reinterpret_cast<const float4*>(x)[i];
        reinterpret_cast<bh4*>(xb)[i] = pack4(v.x, v.y, v.z, v.w);
    } else if (bid < 11264) {
        int j = bid - 8192;                       // 0..3071
        int sel = j >> 10;
        const float* src = (sel == 0) ? w0 : (sel == 1) ? w1 : w2;
        int i = (j & 1023) * 256 + threadIdx.x;
        float4 v = reinterpret_cast<const float4*>(src)[i];
        reinterpret_cast<bh4*>(wb + (size_t)sel * 1048576)[i] =
            pack4(v.x, v.y, v.z, v.w);
    } else {
        Lbuf[(bid - 11264) * 256 + threadIdx.x] = 0.f;
    }
}

// ---------------------------------------------------------------- helpers
__device__ __forceinline__ void load_lds16(const void* g, void* l) {
    __builtin_amdgcn_global_load_lds(
        (const __attribute__((address_space(1))) void*)g,
        (__attribute__((address_space(3))) void*)l, 16, 0, 0);
}

// ================================================================ QKV core
// C = A[8192,1024] * B[3072,1024]^T. Block 256x128, 4 waves, wave 128x64.
// Q/K cols -> qkv rows; V cols (ct>=16) -> vT[b][d][t] transposed.
__global__ __launch_bounds__(256, 2) void qkv_gemm(
    const __hip_bfloat16* __restrict__ Abase,
    const __hip_bfloat16* __restrict__ Bbase,
    __hip_bfloat16* __restrict__ qkvOut,
    __hip_bfloat16* __restrict__ vTout)
{
    const int bid = blockIdx.x;               // 0..767 (768 = 8 XCD x 96)
    const int xcd = bid & 7;
    const int ii  = bid >> 3;                 // 0..95
    const int rt  = (xcd << 2) | (ii & 3);    // 0..31 (rows of 256)
    const int ct  = ii >> 2;                  // 0..23 (cols of 128)

    __shared__ short lsA[2][256 * 32];        // 32 KiB
    __shared__ short lsB[2][128 * 32];        // 16 KiB

    const int tid  = threadIdx.x;
    const int wave = tid >> 6;
    const int lane = tid & 63;
    const int wr   = (wave >> 1) * 128;       // wave row base in tile
    const int wc   = (wave &  1) * 64;        // wave col base in tile
    const int sr   = lane >> 2;               // staging row 0..15
    // T2 swizzle (all row-base offsets are 0 mod 16 so they drop out):
    const int scol = ((lane & 3) ^ ((lane >> 3) & 3)) * 8;
    const int frow = lane & 15;
    const int fk   = ((lane >> 4) ^ ((lane >> 1) & 3)) * 8;

    const short* A = (const short*)Abase + (long)rt * 256 * 1024;
    const short* B = (const short*)Bbase + (long)ct * 128 * 1024;

    f32x4 acc[8][4] = {};

    for (int k0 = 0; k0 < 1024; k0 += 64) {
        const short* ga = A + (long)(wave * 64 + sr) * 1024 + k0 + scol;
        const short* gb = B + (long)(wave * 32 + sr) * 1024 + k0 + scol;
        // B (W-panel, L3-latency) first so its latency leads the drain.
        #pragma unroll
        for (int i = 0; i < 2; ++i) {
            load_lds16(gb + (long)i * 16384,      &lsB[0][(wave * 32 + i * 16) * 32]);
            load_lds16(gb + (long)i * 16384 + 32, &lsB[1][(wave * 32 + i * 16) * 32]);
        }
        #pragma unroll
        for (int i = 0; i < 4; ++i) {
            load_lds16(ga + (long)i * 16384,      &lsA[0][(wave * 64 + i * 16) * 32]);
            load_lds16(ga + (long)i * 16384 + 32, &lsA[1][(wave * 64 + i * 16) * 32]);
        }
        __syncthreads();

        #pragma unroll
        for (int sub = 0; sub < 2; ++sub) {
            bf16x8 af[8], bfr[4];
            #pragma unroll
            for (int m = 0; m < 8; ++m)
                af[m] = *(const bf16x8*)&lsA[sub][(wr + m * 16 + frow) * 32 + fk];
            #pragma unroll
            for (int n = 0; n < 4; ++n)
                bfr[n] = *(const bf16x8*)&lsB[sub][(wc + n * 16 + frow) * 32 + fk];
            #pragma unroll
            for (int m = 0; m < 8; ++m)
                #pragma unroll
                for (int n = 0; n < 4; ++n)
                    acc[m][n] = __builtin_amdgcn_mfma_f32_16x16x32_bf16(
                        af[m], bfr[n], acc[m][n], 0, 0, 0);
        }
        __syncthreads();
    }

    // epilogue: C/D layout col = lane&15, row = (lane>>4)*4 + reg
    const long crow0 = (long)rt * 256 + wr;
    const long ccol0 = (long)ct * 128 + wc;
    const int  orow  = (lane >> 4) * 4;
    const int  ocol  = lane & 15;

    if (ct >= 16) {
        // V columns: store transposed into vT[b][d][t] (d = col-2048).
        #pragma unroll
        for (int m = 0; m < 8; ++m) {
            const long rowb = crow0 + m * 16 + orow;   // multiple of 4
            const long b    = rowb >> 11;
            const long t0   = rowb & 2047;
            #pragma unroll
            for (int n = 0; n < 4; ++n) {
                const long d = ccol0 + n * 16 + ocol - 2048;
                bh4 pk = pack4(acc[m][n][0], acc[m][n][1],
                               acc[m][n][2], acc[m][n][3]);
                *(bh4*)&vTout[((b << 10) + d) * 2048 + t0] = pk;
            }
        }
    } else {                                  // Q/K columns: plain row store
        #pragma unroll
        for (int m = 0; m < 8; ++m)
            #pragma unroll
            for (int n = 0; n < 4; ++n)
                #pragma unroll
                for (int r = 0; r < 4; ++r)
                    qkvOut[(crow0 + m * 16 + orow + r) * 3072 +
                           ccol0 + n * 16 + ocol] =
                        __float2bfloat16(acc[m][n][r]);
    }
}

// ================================================================ S core
// Thin 128x128 core, 544 blocks, 3 blocks/CU. XCD-grouped triangle:
// half0 rts {12..15, 0..3}, half1 {8..11, 4..7}; counts rt+1 (68/XCD).
__device__ __constant__ int S_RT0[8] = {12, 13, 14, 15, 0, 1, 2, 3};
__device__ __constant__ int S_RT1[8] = {8, 9, 10, 11, 4, 5, 6, 7};

__global__ __launch_bounds__(256, 3) void s_gemm(
    const __hip_bfloat16* __restrict__ QKV,
    __hip_bfloat16* __restrict__ P,
    float* __restrict__ Lbuf)
{
    const int bid = blockIdx.x;               // 0..543
    const int xcd = bid & 7;
    const int bz  = xcd >> 1;
    const int* rts = (xcd & 1) ? S_RT1 : S_RT0;
    int idx = bid >> 3;                       // 0..67
    int seg = 0;
    while (idx >= rts[seg] + 1) { idx -= rts[seg] + 1; ++seg; }
    const int rt = rts[seg];
    const int ct = idx;

    __shared__ short lsA[2][128 * 32];
    __shared__ short lsB[2][128 * 32];

    const int tid  = threadIdx.x;
    const int wave = tid >> 6;
    const int lane = tid & 63;
    const int wr   = (wave >> 1) * 64;
    const int wc   = (wave &  1) * 64;
    const int srow = wave * 32 + (lane >> 2);
    const int scol = ((lane & 3) ^ ((lane >> 3) & 3)) * 8;   // T2 swizzle
    const int frow = lane & 15;
    const int fk   = ((lane >> 4) ^ ((lane >> 1) & 3)) * 8;

    const short* A = (const short*)QKV + (long)bz * 6291456
                   + (long)rt * 128 * 3072;            // Q rows
    const short* B = (const short*)QKV + (long)bz * 6291456 + 1024
                   + (long)ct * 128 * 3072;            // K rows

    f32x4 acc[4][4] = {};

    for (int k0 = 0; k0 < 1024; k0 += 64) {
        const short* ga = A + (long)srow * 3072 + k0 + scol;
        const short* gb = B + (long)srow * 3072 + k0 + scol;
        load_lds16(gb,                   &lsB[0][(wave * 32) * 32]);
        load_lds16(gb + 16L * 3072,      &lsB[0][(wave * 32 + 16) * 32]);
        load_lds16(gb + 32,              &lsB[1][(wave * 32) * 32]);
        load_lds16(gb + 16L * 3072 + 32, &lsB[1][(wave * 32 + 16) * 32]);
        load_lds16(ga,                   &lsA[0][(wave * 32) * 32]);
        load_lds16(ga + 16L * 3072,      &lsA[0][(wave * 32 + 16) * 32]);
        load_lds16(ga + 32,              &lsA[1][(wave * 32) * 32]);
        load_lds16(ga + 16L * 3072 + 32, &lsA[1][(wave * 32 + 16) * 32]);
        __syncthreads();

        #pragma unroll
        for (int sub = 0; sub < 2; ++sub) {
            bf16x8 af[4], bfr[4];
            #pragma unroll
            for (int m = 0; m < 4; ++m)
                af[m] = *(const bf16x8*)&lsA[sub][(wr + m * 16 + frow) * 32 + fk];
            #pragma unroll
            for (int n = 0; n < 4; ++n)
                bfr[n] = *(const bf16x8*)&lsB[sub][(wc + n * 16 + frow) * 32 + fk];
            #pragma unroll
            for (int m = 0; m < 4; ++m)
                #pragma unroll
                for (int n = 0; n < 4; ++n)
                    acc[m][n] = __builtin_amdgcn_mfma_f32_16x16x32_bf16(
                        af[m], bfr[n], acc[m][n], 0, 0, 0);
        }
        __syncthreads();
    }

    // epilogue: exp(s/32) masked + scalar per-(m,r) rowsum (low VGPR)
    const long crow0 = (long)rt * 128 + wr;
    const long ccol0 = (long)ct * 128 + wc;
    const int  orow  = (lane >> 4) * 4;
    const int  ocol  = lane & 15;
    __hip_bfloat16* C = P + (long)bz * 4194304;

    #pragma unroll
    for (int m = 0; m < 4; ++m)
        #pragma unroll
        for (int r = 0; r < 4; ++r) {
            const long row = crow0 + m * 16 + orow + r;
            float sum = 0.f;
            #pragma unroll
            for (int n = 0; n < 4; ++n) {
                const long col = ccol0 + n * 16 + ocol;
                float p = (col <= row) ? __expf(acc[m][n][r] * 0.03125f) : 0.f;
                C[row * 2048 + col] = __float2bfloat16(p);
                sum += p;
            }
            sum += __shfl_xor(sum, 1);
            sum += __shfl_xor(sum, 2);
            sum += __shfl_xor(sum, 4);
            sum += __shfl_xor(sum, 8);
            if ((lane & 15) == 0)
                atomicAdd(&Lbuf[bz * T_SEQ + row], sum);
        }
}

// ---------------------------------------------------------------- PV split-K
// 768 blocks = 8 XCD-groups x 96. xcd -> (bz = xcd>>1, half = xcd&1).
// Balanced p-remap: a = idx>>5, c = idx&31, ct = c&7,
//   p = a==0 ? c>>3 : a==1 ? 7-(c>>3) : 8+(c>>3)
// -> every in-order dispatch triple {a=0,1,2} sums to exactly 17 units.
// half0: p<8  -> direct rt=p, full K, scaled -> d_out  (vT t<1024 only)
//        p>=8 -> part0 rt=p (8..11), K tiles [0,8)     -> d_out unscaled
// half1: p<4  -> part0 rt=12+p, K tiles [0,8)          -> d_out unscaled
//        p>=4 -> part1 rt=8+(p-4)=4+p, K [1024,(rt+1)*128) -> tmp1
// pv_finish combines rows >= 1024.
__global__ __launch_bounds__(256, 3) void pv_split(
    const __hip_bfloat16* __restrict__ P,
    const __hip_bfloat16* __restrict__ Vt,
    float* __restrict__ out,
    float* __restrict__ tmp1,
    const float* __restrict__ Lbuf)
{
    const int bid  = blockIdx.x;             // 0..767
    const int xcd  = bid & 7;
    const int bz   = xcd >> 1;
    const int half = xcd & 1;
    const int idx  = bid >> 3;               // 0..95
    const int a    = idx >> 5;               // 0..2
    const int c    = idx & 31;
    const int ct   = c & 7;
    const int p    = (a == 0) ? (c >> 3) : (a == 1) ? (7 - (c >> 3)) : (8 + (c >> 3));

    int rt, k0s, k0e;
    bool scaled = false;
    float* dst;
    if (half == 0) {
        if (p < 8) {
            rt = p; k0s = 0; k0e = (rt + 1) * 128; scaled = true;
            dst = out + (long)bz * 2097152 + (long)rt * 128 * 1024;
        } else {
            rt = p;  // 8..11
            k0s = 0; k0e = 1024;
            dst = out + (long)bz * 2097152 + (long)rt * 128 * 1024;
        }
    } else {
        if (p < 4) {
            rt = 12 + p; k0s = 0; k0e = 1024;
            dst = out + (long)bz * 2097152 + (long)rt * 128 * 1024;
        } else {
            rt = 4 + p;  // 8..15
            k0s = 1024; k0e = (rt + 1) * 128;
            dst = tmp1 + ((long)bz * 1024 + (long)(rt - 8) * 128) * 1024;
        }
    }

    __shared__ short lsA[2][128 * 32];
    __shared__ short lsB[2][128 * 32];

    const int tid  = threadIdx.x;
    const int wave = tid >> 6;
    const int lane = tid & 63;
    const int wr   = (wave >> 1) * 64;
    const int wc   = (wave &  1) * 64;
    const int srow = wave * 32 + (lane >> 2);
    const int scol = ((lane & 3) ^ ((lane >> 3) & 3)) * 8;   // T2 swizzle
    const int frow = lane & 15;
    const int fk   = ((lane >> 4) ^ ((lane >> 1) & 3)) * 8;

    const short* A = (const short*)P  + (long)bz * 4194304 + (long)rt * 128 * 2048;
    const short* B = (const short*)Vt + (long)bz * 2097152 + (long)ct * 128 * 2048;

    f32x4 acc[4][4] = {};

    for (int k0 = k0s; k0 < k0e; k0 += 64) {
        const short* ga = A + (long)srow * 2048 + k0 + scol;
        const short* gb = B + (long)srow * 2048 + k0 + scol;
        load_lds16(gb,                   &lsB[0][(wave * 32) * 32]);
        load_lds16(gb + 16L * 2048,      &lsB[0][(wave * 32 + 16) * 32]);
        load_lds16(gb + 32,              &lsB[1][(wave * 32) * 32]);
        load_lds16(gb + 16L * 2048 + 32, &lsB[1][(wave * 32 + 16) * 32]);
        load_lds16(ga,                   &lsA[0][(wave * 32) * 32]);
        load_lds16(ga + 16L * 2048,      &lsA[0][(wave * 32 + 16) * 32]);
        load_lds16(ga + 32,              &lsA[1][(wave * 32) * 32]);
        load_lds16(ga + 16L * 2048 + 32, &lsA[1][(wave * 32 + 16) * 32]);
        __syncthreads();

        #pragma unroll
        for (int sub = 0; sub < 2; ++sub) {
            bf16x8 af[4], bfr[4];
            #pragma unroll
            for (int m = 0; m < 4; ++m)
                af[m] = *(const bf16x8*)&lsA[sub][(wr + m * 16 + frow) * 32 + fk];
            #pragma unroll
            for (int n = 0; n < 4; ++n)
                bfr[n] = *(const bf16x8*)&lsB[sub][(wc + n * 16 + frow) * 32 + fk];
            #pragma unroll
            for (int m = 0; m < 4; ++m)
                #pragma unroll
                for (int n = 0; n < 4; ++n)
                    acc[m][n] = __builtin_amdgcn_mfma_f32_16x16x32_bf16(
                        af[m], bfr[n], acc[m][n], 0, 0, 0);
        }
        __syncthreads();
    }

    const int orow = (lane >> 4) * 4;
    const int ocol = lane & 15;
    if (scaled) {
        const float* il = Lbuf + bz * T_SEQ + (long)rt * 128;
        #pragma unroll
        for (int m = 0; m < 4; ++m)
            #pragma unroll
            for (int r = 0; r < 4; ++r) {
                const long lrow = wr + m * 16 + orow + r;
                const float s = 1.f / il[lrow];
                #pragma unroll
                for (int n = 0; n < 4; ++n)
                    dst[lrow * 1024 + ct * 128 + wc + n * 16 + ocol] =
                        acc[m][n][r] * s;
            }
    } else {
        #pragma unroll
        for (int m = 0; m < 4; ++m)
            #pragma unroll
            for (int r = 0; r < 4; ++r) {
                const long lrow = wr + m * 16 + orow + r;
                #pragma unroll
                for (int n = 0; n < 4; ++n)
                    dst[lrow * 1024 + ct * 128 + wc + n * 16 + ocol] = acc[m][n][r];
            }
    }
}

// ---------------------------------------------------------------- PV finish
// rows >= 1024 per batch: out = (out + tmp1) / l.
__global__ void pv_finish(float* __restrict__ out,
                          const float* __restrict__ tmp1,
                          const float* __restrict__ Lbuf) {
    const int g = blockIdx.x;                // 0..4095
    const int b = g >> 10;
    const int r = (g & 1023) + 1024;
    const int c = threadIdx.x * 4;
    const float s = 1.f / Lbuf[b * T_SEQ + r];
    float* po = out + (long)b * 2097152 + (long)r * 1024 + c;
    float4 o = *(const float4*)po;
    float4 t = *(const float4*)&tmp1[((long)b * 1024 + (r - 1024)) * 1024 + c];
    o.x = (o.x + t.x) * s; o.y = (o.y + t.y) * s;
    o.z = (o.z + t.z) * s; o.w = (o.w + t.w) * s;
    *(float4*)po = o;
}

// ---------------------------------------------------------------- launch
extern "C" void kernel_launch(void* const* d_in, const int* in_sizes, int n_in,
                              void* d_out, int out_size, void* d_ws, size_t ws_size,
                              hipStream_t stream) {
    const float* x  = (const float*)d_in[0];
    const float* Wq = (const float*)d_in[1];
    const float* Wk = (const float*)d_in[2];
    const float* Wv = (const float*)d_in[3];

    char* ws = (char*)d_ws;
    // workspace (bytes):
    //   xb   @ 0         : 16,777,216   (dead after QKV; tmp1 aliases)
    //   wb   @ 16777216  :  6,291,456
    //   qkv  @ 23068672  : 50,331,648   (Q|K cols used; V cols unwritten)
    //   vT   @ 73400320  : 16,777,216
    //   P    @ 90177536  : 33,554,432
    //   l    @ 123731968 :     32,768
    __hip_bfloat16* xb   = (__hip_bfloat16*)(ws);
    __hip_bfloat16* wb   = (__hip_bfloat16*)(ws + 16777216);
    __hip_bfloat16* qkv  = (__hip_bfloat16*)(ws + 23068672);
    __hip_bfloat16* vT   = (__hip_bfloat16*)(ws + 73400320);
    __hip_bfloat16* P    = (__hip_bfloat16*)(ws + 90177536);
    float*          Lbuf = (float*)        (ws + 123731968);
    float*          tmp1 = (float*)        (ws);              // aliases xb

    // 1) casts + Lbuf zero
    cast_all<<<dim3(11296), 256, 0, stream>>>(x, Wq, Wk, Wv, xb, wb, Lbuf);

    // 2) fused QKV; fat-wave 256x128 core. Q/K -> qkv, V -> vT transposed
    qkv_gemm<<<dim3(768), 256, 0, stream>>>(xb, wb, qkv, vT);

    // 3) P = exp(mask(QK^T)/32) bf16 + atomic rowsums; thin core, 3/CU
    s_gemm<<<dim3(544), 256, 0, stream>>>(qkv, P, Lbuf);

    // 4) O = P @ V ; XCD-grouped balanced split-K
    pv_split<<<dim3(768), 256, 0, stream>>>(
        P, vT, (float*)d_out, tmp1, Lbuf);

    // 5) combine + scale split rows
    pv_finish<<<dim3(4096), 256, 0, stream>>>((float*)d_out, tmp1, Lbuf);
}